// Round 1
// baseline (405.655 us; speedup 1.0000x reference)
//
#include <hip/hip_runtime.h>
#include <hip/hip_bf16.h>
#include <math.h>

typedef _Float16 f16;
typedef _Float16 f16x8 __attribute__((ext_vector_type(8)));
typedef _Float16 f16x4 __attribute__((ext_vector_type(4)));
typedef float    f32x4 __attribute__((ext_vector_type(4)));

#define NN 1024      // nodes
#define EE 2048      // edges
#define DD 256       // hidden
#define EDH 128      // edge-MLP hidden
#define KTOT 33280   // 256*128 (W2 channels, d-major) + 256 (bias ch) + 256 (root ch)
#define SCAP 16      // LDS-staged edges per node in scatter

// ---------------- small elementwise / prep kernels ----------------

__global__ __launch_bounds__(256) void k_embed(const float* __restrict__ x,
    const float* __restrict__ lw, const float* __restrict__ lb, float* __restrict__ y) {
  int n = blockIdx.x, t = threadIdx.x;
  __shared__ float xr[38];
  if (t < 38) xr[t] = x[n*38 + t];
  __syncthreads();
  float s = lb[t];
  const float* w = lw + t*38;
  #pragma unroll
  for (int d = 0; d < 38; d++) s += xr[d] * w[d];
  y[n*DD + t] = s;
}

__global__ __launch_bounds__(256) void k_bnstat(const float* __restrict__ y,
    float* __restrict__ colsum, float* __restrict__ colsq) {
  int b = blockIdx.x, t = threadIdx.x;
  float s = 0.f, q = 0.f;
  #pragma unroll
  for (int r = 0; r < 4; r++) { float v = y[(b*4 + r)*DD + t]; s += v; q += v*v; }
  atomicAdd(&colsum[t], s); atomicAdd(&colsq[t], q);
}

__global__ __launch_bounds__(256) void k_bnfin(const float* __restrict__ colsum,
    const float* __restrict__ colsq, const float* __restrict__ g, const float* __restrict__ b,
    float* __restrict__ scale, float* __restrict__ shift) {
  int t = threadIdx.x;
  float mean = colsum[t] * (1.f/1024.f);
  float var  = colsq[t] * (1.f/1024.f) - mean*mean;
  float sc = g[t] / sqrtf(var + 1e-5f);
  scale[t] = sc; shift[t] = b[t] - mean*sc;
}

__global__ __launch_bounds__(256) void k_bnapply(const float* __restrict__ y,
    const float* __restrict__ scale, const float* __restrict__ shift,
    float* __restrict__ xh, f16* __restrict__ xh16) {
  int i = blockIdx.x*256 + threadIdx.x;
  int c = i & 255;
  float v = y[i]*scale[c] + shift[c];
  xh[i] = v; xh16[i] = (f16)v;
}

__global__ __launch_bounds__(256) void k_hidden(const float* __restrict__ ea,
    const float* __restrict__ w1, const float* __restrict__ b1, float* __restrict__ hid) {
  int t = threadIdx.x;
  int e = blockIdx.x*2 + (t >> 7);
  int k = t & 127;
  const float* a = ea + e*4;
  const float* w = w1 + k*4;
  float s = b1[k] + a[0]*w[0] + a[1]*w[1] + a[2]*w[2] + a[3]*w[3];
  hid[e*EDH + k] = 1.f / (1.f + expf(-s));
}

// ---------------- CSR build ----------------

__global__ __launch_bounds__(256) void k_cnt(const int* __restrict__ dst, int* __restrict__ cnt) {
  int e = blockIdx.x*256 + threadIdx.x;
  atomicAdd(&cnt[dst[e]], 1);
}

__global__ __launch_bounds__(1024) void k_scan(const int* __restrict__ cnt,
    int* __restrict__ off, int* __restrict__ cursor, float* __restrict__ denom) {
  __shared__ int sc[1024];
  int t = threadIdx.x;
  int c = cnt[t];
  sc[t] = c; __syncthreads();
  for (int o = 1; o < 1024; o <<= 1) {
    int v = (t >= o) ? sc[t - o] : 0;
    __syncthreads();
    sc[t] += v;
    __syncthreads();
  }
  int ex = sc[t] - c;
  off[t] = ex; cursor[t] = ex;
  denom[t] = (float)(c > 1 ? c : 1);
}

__global__ __launch_bounds__(256) void k_fill(const int* __restrict__ dst,
    int* __restrict__ cursor, int* __restrict__ eord) {
  int e = blockIdx.x*256 + threadIdx.x;
  int p = atomicAdd(&cursor[dst[e]], 1);
  eord[p] = e;
}

// ---------------- weight reshapes (per-launch, deterministic) ----------------

// BmatT[f][d*128+k] = nn_w2[(d*256+f)*128 + k]  (coalesced read & write)
__global__ __launch_bounds__(256) void k_w2t(const float* __restrict__ w2, f16* __restrict__ Bm) {
  int gid = blockIdx.x*256 + threadIdx.x;   // 2,097,152 = 256f * 256d * 32
  int f = gid >> 13;
  int rem = gid & 8191;
  int d = rem >> 5;
  int k4 = (rem & 31) << 2;
  f32x4 v = *(const f32x4*)(w2 + (size_t)(d*256 + f)*128 + k4);
  f16x4 r; r[0]=(f16)v[0]; r[1]=(f16)v[1]; r[2]=(f16)v[2]; r[3]=(f16)v[3];
  *(f16x4*)(Bm + (size_t)f*KTOT + d*128 + k4) = r;
}

// bias channel: Bm[f][32768+d] = nn_b2[d*256+f];  root channel: Bm[f][33024+d] = root_w[f*256+d]
__global__ __launch_bounds__(256) void k_w2aux(const float* __restrict__ nb2,
    const float* __restrict__ rw, f16* __restrict__ Bm) {
  int gid = blockIdx.x*256 + threadIdx.x;   // 131072
  int f = (gid >> 8) & 255;
  int d = gid & 255;
  if (gid < 65536) Bm[(size_t)f*KTOT + 32768 + d] = (f16)nb2[d*256 + f];
  else             Bm[(size_t)f*KTOT + 33024 + d] = (f16)rw[f*256 + d];
}

__global__ __launch_bounds__(256) void k_cast4(const float* __restrict__ src,
    f16* __restrict__ dst, int n4) {
  int i = blockIdx.x*256 + threadIdx.x;
  if (i >= n4) return;
  f32x4 v = ((const f32x4*)src)[i];
  f16x4 r; r[0]=(f16)v[0]; r[1]=(f16)v[1]; r[2]=(f16)v[2]; r[3]=(f16)v[3];
  ((f16x4*)dst)[i] = r;
}

// ---------------- scatter: S[n][d*128+k] = sum_{e in in(n)} hid[e,k]*x[src(e),d] ----------------
// plus channel 32768+d = sum_e x[src,d], channel 33024+d = denom[n]*x[n,d]

__global__ __launch_bounds__(256) void k_scatter(const float* __restrict__ xc,
    const float* __restrict__ hid, const int* __restrict__ ei, const int* __restrict__ cnt,
    const int* __restrict__ offn, const int* __restrict__ eord,
    const float* __restrict__ denomB, f16* __restrict__ S) {
  int n = blockIdx.x, t = threadIdx.x;   // t = d
  __shared__ float xls[SCAP][DD];
  __shared__ float hls[SCAP][EDH];
  int deg = cnt[n], o = offn[n];
  int stg = deg < SCAP ? deg : SCAP;
  for (int j = 0; j < stg; j++) {
    int e = eord[o + j];
    int s = ei[e];                       // src
    xls[j][t] = xc[s*DD + t];
    if (t < EDH) hls[j][t] = hid[e*EDH + t];
  }
  __syncthreads();
  f16* Sn = S + (size_t)n*KTOT;
  float xsum = 0.f;
  for (int j = 0; j < stg; j++) xsum += xls[j][t];
  for (int j = SCAP; j < deg; j++) { int e = eord[o+j]; xsum += xc[ei[e]*DD + t]; }
  for (int kb = 0; kb < 16; kb++) {
    float acc[8] = {0,0,0,0,0,0,0,0};
    for (int j = 0; j < stg; j++) {
      float xv = xls[j][t];
      #pragma unroll
      for (int q = 0; q < 8; q++) acc[q] += hls[j][kb*8 + q] * xv;
    }
    for (int j = SCAP; j < deg; j++) {   // rare overflow path, correctness only
      int e = eord[o+j];
      float xv = xc[ei[e]*DD + t];
      #pragma unroll
      for (int q = 0; q < 8; q++) acc[q] += hid[e*EDH + kb*8 + q] * xv;
    }
    f16x8 pk;
    #pragma unroll
    for (int q = 0; q < 8; q++) pk[q] = (f16)acc[q];
    *(f16x8*)(Sn + t*128 + kb*8) = pk;
  }
  Sn[32768 + t] = (f16)xsum;
  Sn[33024 + t] = (f16)(denomB[n] * xc[n*DD + t]);
}

// ---------------- generic MFMA GEMM: C[M,N] = A[M,K] * BT[N,K]^T ----------------
// MODE 0: split-K over blockIdx.z, store f32 partial at C + z*bsC
// MODE 1: store f32
// MODE 3: bias + relu, store f16 (batched over blockIdx.z)

template<int MODE>
__global__ __launch_bounds__(256) void k_gemm(const f16* __restrict__ A,
    const f16* __restrict__ BT, float* __restrict__ C, f16* __restrict__ Ch,
    const float* __restrict__ bias, int M, int N, int K, int kChunk,
    int bsA, int bsB, int bsC, int bsBias) {
  __shared__ __align__(16) f16 As[128*40];
  __shared__ __align__(16) f16 Bs[128*40];
  int t = threadIdx.x;
  int m0 = blockIdx.x*128, n0 = blockIdx.y*128, z = blockIdx.z;
  A  += (size_t)z * bsA;
  BT += (size_t)z * bsB;
  if constexpr (MODE == 0) C += (size_t)z * bsC;
  if constexpr (MODE == 3) { Ch += (size_t)z * bsC; bias += (size_t)z * bsBias; }
  int k0 = (MODE == 0) ? z * kChunk : 0;
  int kend = k0 + kChunk;
  int lane = t & 63, wv = t >> 6, wm = wv >> 1, wn = wv & 1;
  int lr = lane & 15, lk = (lane >> 4) * 8;
  int arow = t >> 2, aseg = (t & 3) * 8;
  f32x4 acc[4][4] = {};
  for (; k0 < kend; k0 += 32) {
    __syncthreads();
    #pragma unroll
    for (int p = 0; p < 2; p++) {
      f16x8 va = *(const f16x8*)(A  + (size_t)(m0 + p*64 + arow)*K + k0 + aseg);
      *(f16x8*)(&As[(p*64 + arow)*40 + aseg]) = va;
      f16x8 vb = *(const f16x8*)(BT + (size_t)(n0 + p*64 + arow)*K + k0 + aseg);
      *(f16x8*)(&Bs[(p*64 + arow)*40 + aseg]) = vb;
    }
    __syncthreads();
    f16x8 af[4], bf[4];
    #pragma unroll
    for (int i = 0; i < 4; i++) af[i] = *(const f16x8*)(&As[(wm*64 + i*16 + lr)*40 + lk]);
    #pragma unroll
    for (int j = 0; j < 4; j++) bf[j] = *(const f16x8*)(&Bs[(wn*64 + j*16 + lr)*40 + lk]);
    #pragma unroll
    for (int i = 0; i < 4; i++)
      #pragma unroll
      for (int j = 0; j < 4; j++)
        acc[i][j] = __builtin_amdgcn_mfma_f32_16x16x32_f16(af[i], bf[j], acc[i][j], 0, 0, 0);
  }
  #pragma unroll
  for (int i = 0; i < 4; i++)
    #pragma unroll
    for (int j = 0; j < 4; j++)
      #pragma unroll
      for (int v = 0; v < 4; v++) {
        int r = m0 + wm*64 + i*16 + (lane >> 4)*4 + v;
        int c = n0 + wn*64 + j*16 + lr;
        float val = acc[i][j][v];
        if constexpr (MODE == 0 || MODE == 1) {
          C[(size_t)r*N + c] = val;
        } else {
          val += bias[c];
          val = fmaxf(val, 0.f);
          Ch[(size_t)r*N + c] = (f16)val;
        }
      }
}

// ---------------- conv epilogue: sum split-K partials, /denom, +bias, relu ----------------

__global__ __launch_bounds__(256) void k_convred(const float* __restrict__ part,
    const float* __restrict__ denomB, const float* __restrict__ cb, f16* __restrict__ m16) {
  int i = blockIdx.x*256 + threadIdx.x;
  float s = 0.f;
  #pragma unroll
  for (int z = 0; z < 16; z++) s += part[(size_t)z*262144 + i];
  int row = i >> 8, c = i & 255;
  float v = s / denomB[row] + cb[c];
  m16[i] = (f16)fmaxf(v, 0.f);
}

// ---------------- GRU gates ----------------

__global__ __launch_bounds__(256) void k_gate(const float* __restrict__ gi,
    const float* __restrict__ gh, const float* __restrict__ bih, const float* __restrict__ bhh,
    const float* __restrict__ hOld, float* __restrict__ hNew, f16* __restrict__ h16) {
  int i = blockIdx.x*256 + threadIdx.x;
  int row = i >> 8, c = i & 255;
  const float* gir = gi + (size_t)row*768;
  const float* ghr = gh + (size_t)row*768;
  float ir  = gir[c]     + bih[c],     hr = ghr[c]     + bhh[c];
  float iz  = gir[256+c] + bih[256+c], hz = ghr[256+c] + bhh[256+c];
  float inn = gir[512+c] + bih[512+c], hn = ghr[512+c] + bhh[512+c];
  float r  = 1.f / (1.f + expf(-(ir + hr)));
  float zz = 1.f / (1.f + expf(-(iz + hz)));
  float nn = tanhf(inn + r*hn);
  float hv = (1.f - zz)*nn + zz*hOld[i];
  hNew[i] = hv; h16[i] = (f16)hv;
}

// ---------------- head tail ----------------

__global__ __launch_bounds__(256) void k_mix(const f16* __restrict__ h2,
    const float* __restrict__ w3, const float* __restrict__ b3, float* __restrict__ mix) {
  int b = blockIdx.x, t = threadIdx.x;
  int wv = t >> 6, lane = t & 63;
  int rid = b*4 + wv;             // 0..10239
  int m = rid >> 10, row = rid & 1023;
  const f16* hr = h2 + (size_t)(m*1024 + row)*DD;
  const float* w = w3 + m*DD;
  float s = 0.f;
  #pragma unroll
  for (int q = 0; q < 4; q++) { int d = lane + q*64; s += (float)hr[d] * w[d]; }
  #pragma unroll
  for (int o = 32; o; o >>= 1) s += __shfl_down(s, o, 64);
  if (lane == 0) mix[m*1024 + row] = s + b3[m];
}

__global__ __launch_bounds__(256) void k_out(const float* __restrict__ mix, float* __restrict__ out) {
  int i = blockIdx.x*256 + threadIdx.x;
  float v[10]; float mu = 0.f;
  #pragma unroll
  for (int m = 0; m < 10; m++) { v[m] = mix[m*1024 + i]; mu += v[m]; }
  mu *= 0.1f;
  float var = 0.f;
  #pragma unroll
  for (int m = 0; m < 10; m++) { float d = v[m] - mu; var += d*d; }
  var *= (1.f/9.f);               // ddof=1
  out[i] = mu;
  out[1024 + i] = sqrtf(var + 1e-5f);
}

// ---------------- launch ----------------

extern "C" void kernel_launch(void* const* d_in, const int* in_sizes, int n_in,
                              void* d_out, int out_size, void* d_ws, size_t ws_size,
                              hipStream_t stream) {
  const float* x         = (const float*)d_in[0];
  const float* edge_attr = (const float*)d_in[1];
  const int*   edge_idx  = (const int*)  d_in[2];
  const float* lin_w     = (const float*)d_in[3];
  const float* lin_b     = (const float*)d_in[4];
  const float* bn_g      = (const float*)d_in[5];
  const float* bn_b      = (const float*)d_in[6];
  const float* nn_w1     = (const float*)d_in[7];
  const float* nn_b1     = (const float*)d_in[8];
  const float* nn_w2     = (const float*)d_in[9];
  const float* nn_b2     = (const float*)d_in[10];
  const float* root_w    = (const float*)d_in[11];
  const float* conv_b    = (const float*)d_in[12];
  const float* gru_wih   = (const float*)d_in[13];
  const float* gru_whh   = (const float*)d_in[14];
  const float* gru_bih   = (const float*)d_in[15];
  const float* gru_bhh   = (const float*)d_in[16];
  const float* mlp_w1    = (const float*)d_in[17];
  const float* mlp_b1    = (const float*)d_in[18];
  const float* mlp_w2    = (const float*)d_in[19];
  const float* mlp_b2    = (const float*)d_in[20];
  const float* mlp_w3    = (const float*)d_in[21];
  const float* mlp_b3    = (const float*)d_in[22];
  float* out = (float*)d_out;

  char* w = (char*)d_ws;
  size_t o = 0;
  auto nxt = [&](size_t b) -> size_t { size_t r = o; o += (b + 255) & ~(size_t)255; return r; };
  float* y      = (float*)(w + nxt(1048576));
  float* colsum = (float*)(w + nxt(1024));
  float* colsq  = (float*)(w + nxt(1024));
  float* scale  = (float*)(w + nxt(1024));
  float* shift  = (float*)(w + nxt(1024));
  float* xh     = (float*)(w + nxt(1048576));
  f16*   xh16   = (f16*)  (w + nxt(524288));
  float* h      = (float*)(w + nxt(1048576));
  f16*   h16    = (f16*)  (w + nxt(524288));
  float* hid    = (float*)(w + nxt(1048576));
  int*   cnt    = (int*)  (w + nxt(4096));
  int*   offn   = (int*)  (w + nxt(4096));
  int*   cursor = (int*)  (w + nxt(4096));
  float* denomB = (float*)(w + nxt(4096));
  int*   eord   = (int*)  (w + nxt(8192));
  f16*   Bm     = (f16*)  (w + nxt((size_t)256*KTOT*2));
  f16*   S      = (f16*)  (w + nxt((size_t)1024*KTOT*2));
  float* part   = (float*)(w + nxt((size_t)16*1024*256*4));
  f16*   m16    = (f16*)  (w + nxt(524288));
  float* gi     = (float*)(w + nxt(3145728));
  float* gh     = (float*)(w + nxt(3145728));
  f16*   wihT   = (f16*)  (w + nxt(393216));
  f16*   whhT   = (f16*)  (w + nxt(393216));
  f16*   w1T    = (f16*)  (w + nxt(1310720));
  f16*   w2T    = (f16*)  (w + nxt(1310720));
  f16*   h1     = (f16*)  (w + nxt(5242880));
  f16*   h2     = (f16*)  (w + nxt(5242880));
  float* mixb   = (float*)(w + nxt(40960));
  if (o > ws_size) return;  // workspace insufficient -> fail loudly via validation

  hipMemsetAsync(colsum, 0, 2048, stream);   // colsum + colsq (contiguous)
  hipMemsetAsync(cnt, 0, 4096, stream);

  k_embed  <<<1024, 256, 0, stream>>>(x, lin_w, lin_b, y);
  k_bnstat <<<256, 256, 0, stream>>>(y, colsum, colsq);
  k_bnfin  <<<1, 256, 0, stream>>>(colsum, colsq, bn_g, bn_b, scale, shift);
  k_bnapply<<<1024, 256, 0, stream>>>(y, scale, shift, xh, xh16);
  k_hidden <<<1024, 256, 0, stream>>>(edge_attr, nn_w1, nn_b1, hid);
  k_cnt    <<<8, 256, 0, stream>>>(edge_idx + EE, cnt);
  k_scan   <<<1, 1024, 0, stream>>>(cnt, offn, cursor, denomB);
  k_fill   <<<8, 256, 0, stream>>>(edge_idx + EE, cursor, eord);
  k_w2t    <<<8192, 256, 0, stream>>>(nn_w2, Bm);
  k_w2aux  <<<512, 256, 0, stream>>>(nn_b2, root_w, Bm);
  k_cast4  <<<192, 256, 0, stream>>>(gru_wih, wihT, 49152);
  k_cast4  <<<192, 256, 0, stream>>>(gru_whh, whhT, 49152);
  k_cast4  <<<640, 256, 0, stream>>>(mlp_w1, w1T, 163840);
  k_cast4  <<<640, 256, 0, stream>>>(mlp_w2, w2T, 163840);

  for (int it = 0; it < 3; it++) {
    const float* xc  = (it == 0) ? xh   : h;
    const f16*   xc16= (it == 0) ? xh16 : h16;
    k_scatter<<<1024, 256, 0, stream>>>(xc, hid, edge_idx, cnt, offn, eord, denomB, S);
    k_gemm<0><<<dim3(8, 2, 16), 256, 0, stream>>>(S, Bm, part, nullptr, nullptr,
                                                  1024, 256, KTOT, 2080, 0, 0, 262144, 0);
    k_convred<<<1024, 256, 0, stream>>>(part, denomB, conv_b, m16);
    k_gemm<1><<<dim3(8, 6, 1), 256, 0, stream>>>(m16, wihT, gi, nullptr, nullptr,
                                                 1024, 768, 256, 256, 0, 0, 0, 0);
    k_gemm<1><<<dim3(8, 6, 1), 256, 0, stream>>>(xc16, whhT, gh, nullptr, nullptr,
                                                 1024, 768, 256, 256, 0, 0, 0, 0);
    k_gate<<<1024, 256, 0, stream>>>(gi, gh, gru_bih, gru_bhh, xc, h, h16);
  }

  k_gemm<3><<<dim3(8, 2, 10), 256, 0, stream>>>(h16, w1T, nullptr, h1, mlp_b1,
                                                1024, 256, 256, 256, 0, 65536, 262144, 256);
  k_gemm<3><<<dim3(8, 2, 10), 256, 0, stream>>>(h1, w2T, nullptr, h2, mlp_b2,
                                                1024, 256, 256, 256, 262144, 65536, 262144, 256);
  k_mix<<<2560, 256, 0, stream>>>(h2, mlp_w3, mlp_b3, mixb);
  k_out<<<4, 256, 0, stream>>>(mixb, out);
}

// Round 2
// 359.915 us; speedup vs baseline: 1.1271x; 1.1271x over previous
//
#include <hip/hip_runtime.h>
#include <hip/hip_bf16.h>
#include <math.h>

typedef _Float16 f16;
typedef _Float16 f16x8 __attribute__((ext_vector_type(8)));
typedef _Float16 f16x4 __attribute__((ext_vector_type(4)));
typedef float    f32x4 __attribute__((ext_vector_type(4)));

#define NN 1024      // nodes
#define EE 2048      // edges
#define DD 256       // hidden
#define EDH 128      // edge-MLP hidden
#define KW 32768     // 256*128 (W2 channels, d-major)
#define SCAP 16      // LDS-staged edges per node in scatter

typedef const __attribute__((address_space(1))) void gas_t;
typedef __attribute__((address_space(3))) void las_t;
#define GLOAD16(g, l) __builtin_amdgcn_global_load_lds((gas_t*)(g), (las_t*)(l), 16, 0, 0)

// ---------------- prep ----------------

// embed + batch-stat accumulate (fused)
__global__ __launch_bounds__(256) void k_embed(const float* __restrict__ x,
    const float* __restrict__ lw, const float* __restrict__ lb, float* __restrict__ y,
    float* __restrict__ colsum, float* __restrict__ colsq) {
  int n = blockIdx.x, t = threadIdx.x;
  __shared__ float xr[38];
  if (t < 38) xr[t] = x[n*38 + t];
  __syncthreads();
  float s = lb[t];
  const float* w = lw + t*38;
  #pragma unroll
  for (int d = 0; d < 38; d++) s += xr[d] * w[d];
  y[n*DD + t] = s;
  atomicAdd(&colsum[t], s);
  atomicAdd(&colsq[t], s*s);
}

// bn normalize (stats finalized in-kernel) -> xh f32, Agru h-half f16
__global__ __launch_bounds__(256) void k_bnapply(const float* __restrict__ y,
    const float* __restrict__ colsum, const float* __restrict__ colsq,
    const float* __restrict__ g, const float* __restrict__ b,
    float* __restrict__ xh, f16* __restrict__ Agru) {
  int i = blockIdx.x*256 + threadIdx.x;
  int c = i & 255, row = i >> 8;
  float mean = colsum[c] * (1.f/1024.f);
  float var  = colsq[c] * (1.f/1024.f) - mean*mean;
  float sc = g[c] / sqrtf(var + 1e-5f);
  float sh = b[c] - mean*sc;
  float v = y[i]*sc + sh;
  xh[i] = v;
  Agru[(size_t)row*512 + 256 + c] = (f16)v;
}

__global__ __launch_bounds__(256) void k_hidden(const float* __restrict__ ea,
    const float* __restrict__ w1, const float* __restrict__ b1, float* __restrict__ hid) {
  int t = threadIdx.x;
  int e = blockIdx.x*2 + (t >> 7);
  int k = t & 127;
  const float* a = ea + e*4;
  const float* w = w1 + k*4;
  float s = b1[k] + a[0]*w[0] + a[1]*w[1] + a[2]*w[2] + a[3]*w[3];
  hid[e*EDH + k] = 1.f / (1.f + expf(-s));
}

// ---------------- CSR build ----------------

__global__ __launch_bounds__(256) void k_cnt(const int* __restrict__ dst, int* __restrict__ cnt) {
  int e = blockIdx.x*256 + threadIdx.x;
  atomicAdd(&cnt[dst[e]], 1);
}

__global__ __launch_bounds__(1024) void k_scan(const int* __restrict__ cnt,
    int* __restrict__ off, int* __restrict__ cursor, float* __restrict__ denom) {
  __shared__ int sc[1024];
  int t = threadIdx.x;
  int c = cnt[t];
  sc[t] = c; __syncthreads();
  for (int o = 1; o < 1024; o <<= 1) {
    int v = (t >= o) ? sc[t - o] : 0;
    __syncthreads();
    sc[t] += v;
    __syncthreads();
  }
  int ex = sc[t] - c;
  off[t] = ex; cursor[t] = ex;
  denom[t] = (float)(c > 1 ? c : 1);
}

__global__ __launch_bounds__(256) void k_fill(const int* __restrict__ dst,
    int* __restrict__ cursor, int* __restrict__ eord) {
  int e = blockIdx.x*256 + threadIdx.x;
  int p = atomicAdd(&cursor[dst[e]], 1);
  eord[p] = e;
}

// ---------------- weight reshapes ----------------

// Bm[f][d*128+k] = nn_w2[(d*256+f)*128 + k]
__global__ __launch_bounds__(256) void k_w2t(const float* __restrict__ w2, f16* __restrict__ Bm) {
  int gid = blockIdx.x*256 + threadIdx.x;   // 2,097,152
  int f = gid >> 13;
  int rem = gid & 8191;
  int d = rem >> 5;
  int k4 = (rem & 31) << 2;
  f32x4 v = *(const f32x4*)(w2 + (size_t)(d*256 + f)*128 + k4);
  f16x4 r; r[0]=(f16)v[0]; r[1]=(f16)v[1]; r[2]=(f16)v[2]; r[3]=(f16)v[3];
  *(f16x4*)(Bm + (size_t)f*KW + d*128 + k4) = r;
}

// Bside[f][c] : c<256 -> nn_b2[c*256+f] ; c>=256 -> root_w[f*256+(c-256)]
__global__ __launch_bounds__(256) void k_sideB(const float* __restrict__ nb2,
    const float* __restrict__ rw, f16* __restrict__ Bside) {
  int i = blockIdx.x*256 + threadIdx.x;    // 131072
  int f = i >> 9, c = i & 511;
  float v = (c < 256) ? nb2[c*256 + f] : rw[f*256 + (c - 256)];
  Bside[(size_t)f*512 + c] = (f16)v;
}

__global__ __launch_bounds__(256) void k_cast4(const float* __restrict__ src,
    f16* __restrict__ dst, int n4) {
  int i = blockIdx.x*256 + threadIdx.x;
  if (i >= n4) return;
  f32x4 v = ((const f32x4*)src)[i];
  f16x4 r; r[0]=(f16)v[0]; r[1]=(f16)v[1]; r[2]=(f16)v[2]; r[3]=(f16)v[3];
  ((f16x4*)dst)[i] = r;
}

// ---------------- scatter: S[n][d*128+k] = sum_e hid[e,k]*x[src,d]; A2 = [xsum | denom*xc] ----------------

__global__ __launch_bounds__(256) void k_scatter(const float* __restrict__ xc,
    const float* __restrict__ hid, const int* __restrict__ ei, const int* __restrict__ cnt,
    const int* __restrict__ offn, const int* __restrict__ eord,
    const float* __restrict__ denomB, f16* __restrict__ S, f16* __restrict__ A2) {
  int n = blockIdx.x, t = threadIdx.x;   // t = d
  __shared__ float xls[SCAP][DD];
  __shared__ float hls[SCAP][EDH];
  int deg = cnt[n], o = offn[n];
  int stg = deg < SCAP ? deg : SCAP;
  for (int j = 0; j < stg; j++) {
    int e = eord[o + j];
    int s = ei[e];
    xls[j][t] = xc[s*DD + t];
    if (t < EDH) hls[j][t] = hid[e*EDH + t];
  }
  __syncthreads();
  f16* Sn = S + (size_t)n*KW;
  float xsum = 0.f;
  for (int j = 0; j < stg; j++) xsum += xls[j][t];
  for (int j = SCAP; j < deg; j++) { int e = eord[o+j]; xsum += xc[ei[e]*DD + t]; }
  for (int kb = 0; kb < 16; kb++) {
    float acc[8] = {0,0,0,0,0,0,0,0};
    for (int j = 0; j < stg; j++) {
      float xv = xls[j][t];
      #pragma unroll
      for (int q = 0; q < 8; q++) acc[q] += hls[j][kb*8 + q] * xv;
    }
    for (int j = SCAP; j < deg; j++) {
      int e = eord[o+j];
      float xv = xc[ei[e]*DD + t];
      #pragma unroll
      for (int q = 0; q < 8; q++) acc[q] += hid[e*EDH + kb*8 + q] * xv;
    }
    f16x8 pk;
    #pragma unroll
    for (int q = 0; q < 8; q++) pk[q] = (f16)acc[q];
    *(f16x8*)(Sn + t*128 + kb*8) = pk;
  }
  A2[(size_t)n*512 + t]       = (f16)xsum;
  A2[(size_t)n*512 + 256 + t] = (f16)(denomB[n] * xc[n*DD + t]);
}

// ---------------- main conv GEMM: part[z] = S[:, z*1024:+1024] @ Bm[:, same]^T ----------------
// 128x128 tile, BK=32, global_load_lds staging (m97 structure), grid (8,2,32)

__global__ __launch_bounds__(256) void k_cgemm(const f16* __restrict__ A,
    const f16* __restrict__ BT, float* __restrict__ part) {
  __shared__ __align__(16) f16 As[128*32];
  __shared__ __align__(16) f16 Bs[128*32];
  int t = threadIdx.x;
  int m0 = blockIdx.x*128, n0 = blockIdx.y*128, z = blockIdx.z;
  int k0 = z << 10;
  int lane = t & 63, wv = t >> 6, wm = wv >> 1, wn = wv & 1;
  int lr = lane & 15, lk = (lane >> 4) * 8;
  // staging geometry: wave wv, instr i: elems [wv*1024 + i*512 + lane*8, +8)
  int e0 = wv*1024 + lane*8;
  int r0 = e0 >> 5, c0 = e0 & 31;
  int e1 = e0 + 512;
  int r1 = e1 >> 5, c1 = e1 & 31;
  const f16* Ag0 = A  + (size_t)(m0 + r0)*KW + k0 + c0;
  const f16* Ag1 = A  + (size_t)(m0 + r1)*KW + k0 + c1;
  const f16* Bg0 = BT + (size_t)(n0 + r0)*KW + k0 + c0;
  const f16* Bg1 = BT + (size_t)(n0 + r1)*KW + k0 + c1;
  f16* Al0 = As + wv*1024;       f16* Al1 = As + wv*1024 + 512;
  f16* Bl0 = Bs + wv*1024;       f16* Bl1 = Bs + wv*1024 + 512;
  f32x4 acc[4][4] = {};
  for (int kk = 0; kk < 1024; kk += 32) {
    __syncthreads();
    GLOAD16(Ag0 + kk, Al0);
    GLOAD16(Ag1 + kk, Al1);
    GLOAD16(Bg0 + kk, Bl0);
    GLOAD16(Bg1 + kk, Bl1);
    __syncthreads();
    f16x8 af[4], bf[4];
    #pragma unroll
    for (int i = 0; i < 4; i++) af[i] = *(const f16x8*)(&As[(wm*64 + i*16 + lr)*32 + lk]);
    #pragma unroll
    for (int j = 0; j < 4; j++) bf[j] = *(const f16x8*)(&Bs[(wn*64 + j*16 + lr)*32 + lk]);
    #pragma unroll
    for (int i = 0; i < 4; i++)
      #pragma unroll
      for (int j = 0; j < 4; j++)
        acc[i][j] = __builtin_amdgcn_mfma_f32_16x16x32_f16(af[i], bf[j], acc[i][j], 0, 0, 0);
  }
  float* C = part + (size_t)z*262144;
  #pragma unroll
  for (int i = 0; i < 4; i++)
    #pragma unroll
    for (int j = 0; j < 4; j++)
      #pragma unroll
      for (int v = 0; v < 4; v++) {
        int r = m0 + wm*64 + i*16 + (lane >> 4)*4 + v;
        int c = n0 + wn*64 + j*16 + lr;
        C[(size_t)r*256 + c] = acc[i][j][v];
      }
}

// ---------------- small GEMM: 64x128 tile. MODE 1: f32 store; MODE 3: bias+relu f16 ----------------

template<int MODE>
__global__ __launch_bounds__(256) void k_gemm_sm(const f16* __restrict__ A,
    const f16* __restrict__ BT, float* __restrict__ C, f16* __restrict__ Ch,
    const float* __restrict__ bias, int K, int lda, int ldb, int N,
    int bsA, int bsB, int bsC, int bsBias) {
  __shared__ __align__(16) f16 As[64*40];
  __shared__ __align__(16) f16 Bs[128*40];
  int t = threadIdx.x;
  int m0 = blockIdx.x*64, n0 = blockIdx.y*128, z = blockIdx.z;
  A  += (size_t)z * bsA;
  BT += (size_t)z * bsB;
  if constexpr (MODE == 1) C += (size_t)z * bsC;
  else { Ch += (size_t)z * bsC; bias += (size_t)z * bsBias; }
  int lane = t & 63, wv = t >> 6, wm = wv >> 1, wn = wv & 1;
  int lr = lane & 15, lk = (lane >> 4) * 8;
  int arow = t >> 2, aseg = (t & 3) * 8;
  f32x4 acc[2][4] = {};
  for (int k0 = 0; k0 < K; k0 += 32) {
    __syncthreads();
    *(f16x8*)(&As[arow*40 + aseg]) = *(const f16x8*)(A + (size_t)(m0 + arow)*lda + k0 + aseg);
    *(f16x8*)(&Bs[arow*40 + aseg]) = *(const f16x8*)(BT + (size_t)(n0 + arow)*ldb + k0 + aseg);
    *(f16x8*)(&Bs[(64+arow)*40 + aseg]) = *(const f16x8*)(BT + (size_t)(n0 + 64 + arow)*ldb + k0 + aseg);
    __syncthreads();
    f16x8 af[2], bf[4];
    #pragma unroll
    for (int i = 0; i < 2; i++) af[i] = *(const f16x8*)(&As[(wm*32 + i*16 + lr)*40 + lk]);
    #pragma unroll
    for (int j = 0; j < 4; j++) bf[j] = *(const f16x8*)(&Bs[(wn*64 + j*16 + lr)*40 + lk]);
    #pragma unroll
    for (int i = 0; i < 2; i++)
      #pragma unroll
      for (int j = 0; j < 4; j++)
        acc[i][j] = __builtin_amdgcn_mfma_f32_16x16x32_f16(af[i], bf[j], acc[i][j], 0, 0, 0);
  }
  #pragma unroll
  for (int i = 0; i < 2; i++)
    #pragma unroll
    for (int j = 0; j < 4; j++)
      #pragma unroll
      for (int v = 0; v < 4; v++) {
        int r = m0 + wm*32 + i*16 + (lane >> 4)*4 + v;
        int c = n0 + wn*64 + j*16 + lr;
        float val = acc[i][j][v];
        if constexpr (MODE == 1) {
          C[(size_t)r*N + c] = val;
        } else {
          val += bias[c];
          val = fmaxf(val, 0.f);
          Ch[(size_t)r*N + c] = (f16)val;
        }
      }
}

// ---------------- conv epilogue: sum 33 partials, /denom, +bias, relu -> Agru m-half ----------------

__global__ __launch_bounds__(256) void k_convred(const float* __restrict__ part,
    const float* __restrict__ denomB, const float* __restrict__ cb, f16* __restrict__ Agru) {
  int i = blockIdx.x*256 + threadIdx.x;
  float s = 0.f;
  #pragma unroll
  for (int z = 0; z < 33; z++) s += part[(size_t)z*262144 + i];
  int row = i >> 8, c = i & 255;
  float v = s / denomB[row] + cb[c];
  Agru[(size_t)row*512 + c] = (f16)fmaxf(v, 0.f);
}

// ---------------- GRU gates ----------------

__global__ __launch_bounds__(256) void k_gate(const float* __restrict__ gi,
    const float* __restrict__ gh, const float* __restrict__ bih, const float* __restrict__ bhh,
    const float* __restrict__ hOld, float* __restrict__ hNew, f16* __restrict__ Agru) {
  int i = blockIdx.x*256 + threadIdx.x;
  int row = i >> 8, c = i & 255;
  const float* gir = gi + (size_t)row*768;
  const float* ghr = gh + (size_t)row*768;
  float ir  = gir[c]     + bih[c],     hr = ghr[c]     + bhh[c];
  float iz  = gir[256+c] + bih[256+c], hz = ghr[256+c] + bhh[256+c];
  float inn = gir[512+c] + bih[512+c], hn = ghr[512+c] + bhh[512+c];
  float r  = 1.f / (1.f + expf(-(ir + hr)));
  float zz = 1.f / (1.f + expf(-(iz + hz)));
  float nn = tanhf(inn + r*hn);
  float hv = (1.f - zz)*nn + zz*hOld[i];
  hNew[i] = hv;
  Agru[(size_t)row*512 + 256 + c] = (f16)hv;
}

// ---------------- head tail ----------------

__global__ __launch_bounds__(256) void k_mix(const f16* __restrict__ h2,
    const float* __restrict__ w3, const float* __restrict__ b3, float* __restrict__ mix) {
  int b = blockIdx.x, t = threadIdx.x;
  int wv = t >> 6, lane = t & 63;
  int rid = b*4 + wv;
  int m = rid >> 10, row = rid & 1023;
  const f16* hr = h2 + (size_t)(m*1024 + row)*DD;
  const float* w = w3 + m*DD;
  float s = 0.f;
  #pragma unroll
  for (int q = 0; q < 4; q++) { int d = lane + q*64; s += (float)hr[d] * w[d]; }
  #pragma unroll
  for (int o = 32; o; o >>= 1) s += __shfl_down(s, o, 64);
  if (lane == 0) mix[m*1024 + row] = s + b3[m];
}

__global__ __launch_bounds__(256) void k_out(const float* __restrict__ mix, float* __restrict__ out) {
  int i = blockIdx.x*256 + threadIdx.x;
  float v[10]; float mu = 0.f;
  #pragma unroll
  for (int m = 0; m < 10; m++) { v[m] = mix[m*1024 + i]; mu += v[m]; }
  mu *= 0.1f;
  float var = 0.f;
  #pragma unroll
  for (int m = 0; m < 10; m++) { float d = v[m] - mu; var += d*d; }
  var *= (1.f/9.f);
  out[i] = mu;
  out[1024 + i] = sqrtf(var + 1e-5f);
}

// ---------------- launch ----------------

extern "C" void kernel_launch(void* const* d_in, const int* in_sizes, int n_in,
                              void* d_out, int out_size, void* d_ws, size_t ws_size,
                              hipStream_t stream) {
  const float* x         = (const float*)d_in[0];
  const float* edge_attr = (const float*)d_in[1];
  const int*   edge_idx  = (const int*)  d_in[2];
  const float* lin_w     = (const float*)d_in[3];
  const float* lin_b     = (const float*)d_in[4];
  const float* bn_g      = (const float*)d_in[5];
  const float* bn_b      = (const float*)d_in[6];
  const float* nn_w1     = (const float*)d_in[7];
  const float* nn_b1     = (const float*)d_in[8];
  const float* nn_w2     = (const float*)d_in[9];
  const float* nn_b2     = (const float*)d_in[10];
  const float* root_w    = (const float*)d_in[11];
  const float* conv_b    = (const float*)d_in[12];
  const float* gru_wih   = (const float*)d_in[13];
  const float* gru_whh   = (const float*)d_in[14];
  const float* gru_bih   = (const float*)d_in[15];
  const float* gru_bhh   = (const float*)d_in[16];
  const float* mlp_w1    = (const float*)d_in[17];
  const float* mlp_b1    = (const float*)d_in[18];
  const float* mlp_w2    = (const float*)d_in[19];
  const float* mlp_b2    = (const float*)d_in[20];
  const float* mlp_w3    = (const float*)d_in[21];
  const float* mlp_b3    = (const float*)d_in[22];
  float* out = (float*)d_out;

  char* w = (char*)d_ws;
  size_t o = 0;
  auto nxt = [&](size_t b) -> size_t { size_t r = o; o += (b + 255) & ~(size_t)255; return r; };
  float* y      = (float*)(w + nxt(1048576));
  float* colsum = (float*)(w + nxt(1024));
  float* colsq  = (float*)(w + nxt(1024));
  float* xh     = (float*)(w + nxt(1048576));
  float* h      = (float*)(w + nxt(1048576));
  float* hid    = (float*)(w + nxt(1048576));
  int*   cnt    = (int*)  (w + nxt(4096));
  int*   offn   = (int*)  (w + nxt(4096));
  int*   cursor = (int*)  (w + nxt(4096));
  float* denomB = (float*)(w + nxt(4096));
  int*   eord   = (int*)  (w + nxt(8192));
  f16*   Bm     = (f16*)  (w + nxt((size_t)256*KW*2));          // 16.8 MB
  f16*   Bside  = (f16*)  (w + nxt(262144));
  f16*   Wb     = (f16*)  (w + nxt(786432));                    // [2][768][256] f16
  f16*   S      = (f16*)  (w + nxt((size_t)1024*KW*2));         // 67 MB
  f16*   A2     = (f16*)  (w + nxt(1048576));                   // [1024][512] f16
  f16*   Agru   = (f16*)  (w + nxt(1048576));                   // [1024][512] f16 = [m | h]
  float* part   = (float*)(w + nxt((size_t)33*1024*256*4));     // 34.6 MB
  float* G      = (float*)(w + nxt((size_t)2*1024*768*4));      // gi, gh
  f16*   h1     = (f16*)  (w + nxt(5242880));
  f16*   h2     = (f16*)  (w + nxt(5242880));
  float* mixb   = (float*)(w + nxt(40960));
  if (o > ws_size) return;

  hipMemsetAsync(colsum, 0, 2048, stream);   // colsum + colsq (contiguous)
  hipMemsetAsync(cnt, 0, 4096, stream);

  k_embed  <<<1024, 256, 0, stream>>>(x, lin_w, lin_b, y, colsum, colsq);
  k_bnapply<<<1024, 256, 0, stream>>>(y, colsum, colsq, bn_g, bn_b, xh, Agru);
  k_hidden <<<1024, 256, 0, stream>>>(edge_attr, nn_w1, nn_b1, hid);
  k_cnt    <<<8, 256, 0, stream>>>(edge_idx + EE, cnt);
  k_scan   <<<1, 1024, 0, stream>>>(cnt, offn, cursor, denomB);
  k_fill   <<<8, 256, 0, stream>>>(edge_idx + EE, cursor, eord);
  k_w2t    <<<8192, 256, 0, stream>>>(nn_w2, Bm);
  k_sideB  <<<512, 256, 0, stream>>>(nn_b2, root_w, Bside);
  k_cast4  <<<192, 256, 0, stream>>>(gru_wih, Wb, 49152);
  k_cast4  <<<192, 256, 0, stream>>>(gru_whh, Wb + 196608, 49152);
  k_cast4  <<<640, 256, 0, stream>>>(mlp_w1, h1 /*reuse later*/, 0);  // no-op placeholder removed below
  // (mlp casts)
  k_cast4  <<<640, 256, 0, stream>>>(mlp_w1, (f16*)(w + o - 1), 0);   // dummy guard (never writes, n4=0)

  // mlp weight casts into dedicated buffers (appended after mixb to keep layout simple)
  // -- allocate here:
  f16* w1T = (f16*)(w + nxt(1310720));
  f16* w2T = (f16*)(w + nxt(1310720));
  if (o > ws_size) return;
  k_cast4  <<<640, 256, 0, stream>>>(mlp_w1, w1T, 163840);
  k_cast4  <<<640, 256, 0, stream>>>(mlp_w2, w2T, 163840);

  for (int it = 0; it < 3; it++) {
    const float* xc = (it == 0) ? xh : h;
    k_scatter<<<1024, 256, 0, stream>>>(xc, hid, edge_idx, cnt, offn, eord, denomB, S, A2);
    k_cgemm  <<<dim3(8, 2, 32), 256, 0, stream>>>(S, Bm, part);
    k_gemm_sm<1><<<dim3(16, 2, 1), 256, 0, stream>>>(A2, Bside, part + (size_t)32*262144,
        nullptr, nullptr, 512, 512, 512, 256, 0, 0, 0, 0);
    k_convred<<<1024, 256, 0, stream>>>(part, denomB, conv_b, Agru);
    // gi = m @ wih^T ; gh = h @ whh^T  (z-batched: A halves of Agru, bsA=256)
    k_gemm_sm<1><<<dim3(16, 6, 2), 256, 0, stream>>>(Agru, Wb, G,
        nullptr, nullptr, 256, 512, 256, 768, 256, 196608, 786432, 0);
    k_gate<<<1024, 256, 0, stream>>>(G, G + 786432, gru_bih, gru_bhh, xc, h, Agru);
  }

  k_gemm_sm<3><<<dim3(16, 2, 10), 256, 0, stream>>>(Agru + 256, w1T, nullptr, h1, mlp_b1,
      256, 512, 256, 256, 0, 65536, 262144, 256);
  k_gemm_sm<3><<<dim3(16, 2, 10), 256, 0, stream>>>(h1, w2T, nullptr, h2, mlp_b2,
      256, 256, 256, 256, 262144, 65536, 262144, 256);
  k_mix<<<2560, 256, 0, stream>>>(h2, mlp_w3, mlp_b3, mixb);
  k_out<<<4, 256, 0, stream>>>(mixb, out);
}